// Round 1
// baseline (162.288 us; speedup 1.0000x reference)
//
#include <hip/hip_runtime.h>

#define DIM   256
#define CLS   512
#define NGF   32640
#define ROWH  264            // _Float16 elements per LDS row (528 B, 16B-aligned, bank-stride 4)
#define NITER 14

typedef _Float16 h16;
typedef __attribute__((ext_vector_type(2))) _Float16 h16x2;

__device__ __forceinline__ float dot2f(unsigned a, unsigned b, float c) {
#if __has_builtin(__builtin_amdgcn_fdot2)
    return __builtin_amdgcn_fdot2(__builtin_bit_cast(h16x2, a),
                                  __builtin_bit_cast(h16x2, b), c, false);
#else
    h16x2 av = __builtin_bit_cast(h16x2, a);
    h16x2 bv = __builtin_bit_cast(h16x2, b);
    return fmaf((float)av[0], (float)bv[0], fmaf((float)av[1], (float)bv[1], c));
#endif
}

// largest i with off(i) = i*(511-i)/2 <= p   (strict-upper triu row index)
__device__ __forceinline__ int row_of(int p) {
    int i = (int)(255.5f - sqrtf(65280.25f - 2.0f * (float)p));
    i = i < 0 ? 0 : (i > 254 ? 254 : i);
    while ((i + 1) * (510 - i) / 2 <= p) ++i;     // off(i+1) <= p -> advance
    while (i > 0 && i * (511 - i) / 2 > p) --i;   // off(i)  > p  -> retreat
    return i;
}

__global__ void __launch_bounds__(256)
cayley_kernel(const float* __restrict__ x, const float* __restrict__ W,
              float* __restrict__ out) {
    extern __shared__ char smem[];
    h16*   sS  = (h16*)smem;                                 // 256*264*2 = 135168 B
    float* sx  = (float*)(smem + DIM * ROWH * 2);            // 1024 B
    h16*   sy0 = (h16*)(smem + DIM * ROWH * 2 + 1024);       // 528 B
    h16*   sy1 = sy0 + ROWH;                                 // 528 B

    const int tid = threadIdx.x;
    const int c   = blockIdx.x;

    // load x column (strided; L2/L3 absorbs), init y0 = x
    float xv = x[(size_t)tid * CLS + c];
    sx[tid]  = xv;
    sy0[tid] = (h16)xv;
    if (tid < ROWH - DIM) { sy0[DIM + tid] = (h16)0.f; sy1[DIM + tid] = (h16)0.f; }
    // zero diagonal and row padding
    sS[tid * ROWH + tid] = (h16)0.f;
    #pragma unroll
    for (int k = DIM; k < ROWH; ++k) sS[tid * ROWH + k] = (h16)0.f;

    // ---- expand packed upper-tri W into full f16 skew matrix in LDS ----
    const float4* Wc4 = (const float4*)(W + (size_t)c * NGF);
    for (int q = tid; q < NGF / 4; q += DIM) {
        float4 w4 = Wc4[q];                                   // coalesced 16B/lane
        float wv[4] = {w4.x, w4.y, w4.z, w4.w};
        int p0 = q * 4;
        #pragma unroll
        for (int e = 0; e < 4; ++e) {
            int p = p0 + e;
            int i = row_of(p);
            int j = p - i * (511 - i) / 2 + i + 1;
            float s = 0.5f * wv[e];
            sS[i * ROWH + j] = (h16)s;                        // S[i][j] = +0.5 w
            sS[j * ROWH + i] = (h16)(-s);                     // S[j][i] = -0.5 w
        }
    }
    __syncthreads();

    // ---- fixed-point iteration y <- x - S y ;  out = x - 2*S*y_last ----
    const uint4* rowp = (const uint4*)(sS + tid * ROWH);      // 33 chunks of 8 f16
    h16* ycur = sy0;
    h16* ynxt = sy1;
    float res = 0.f;

    for (int it = 0; it < NITER; ++it) {
        const uint4* yp = (const uint4*)ycur;                 // uniform addr: broadcast reads
        float a0 = 0.f, a1 = 0.f, a2 = 0.f, a3 = 0.f;
        #pragma unroll
        for (int k = 0; k < ROWH / 8; ++k) {
            uint4 rv = rowp[k];
            uint4 yv = yp[k];
            a0 = dot2f(rv.x, yv.x, a0);
            a1 = dot2f(rv.y, yv.y, a1);
            a2 = dot2f(rv.z, yv.z, a2);
            a3 = dot2f(rv.w, yv.w, a3);
        }
        float Sy = (a0 + a1) + (a2 + a3);                     // (S y)_row  (0.5 baked into S)
        if (it < NITER - 1) {
            ynxt[tid] = (h16)(sx[tid] - Sy);
            h16* t = ycur; ycur = ynxt; ynxt = t;
            __syncthreads();
        } else {
            res = sx[tid] - 2.0f * Sy;                        // out = 2y - x = x - 2*S*y_prev
        }
    }
    out[(size_t)tid * CLS + c] = res;
}

extern "C" void kernel_launch(void* const* d_in, const int* in_sizes, int n_in,
                              void* d_out, int out_size, void* d_ws, size_t ws_size,
                              hipStream_t stream) {
    const float* x = (const float*)d_in[0];
    const float* W = (const float*)d_in[1];
    float* out = (float*)d_out;

    const size_t smem = (size_t)DIM * ROWH * 2 + 1024 + 2 * (size_t)ROWH * 2; // 137248 B
    hipFuncSetAttribute((const void*)cayley_kernel,
                        hipFuncAttributeMaxDynamicSharedMemorySize, (int)smem);
    hipLaunchKernelGGL(cayley_kernel, dim3(CLS), dim3(DIM), smem, stream, x, W, out);
}

// Round 2
// 97.108 us; speedup vs baseline: 1.6712x; 1.6712x over previous
//
#include <hip/hip_runtime.h>

#define DIM   256
#define CLS   512
#define NGF   32640
#define NITER 10
#define RSH   288   // row stride in h16  (4 parts * 72)
#define PSH   72    // part stride in h16 (64 data + 8 pad -> 36 dwords, bank shift 4)

typedef _Float16 h16;
typedef __attribute__((ext_vector_type(2))) _Float16 h16x2;

__device__ __forceinline__ float dot2f(unsigned a, unsigned b, float c) {
#if __has_builtin(__builtin_amdgcn_fdot2)
    return __builtin_amdgcn_fdot2(__builtin_bit_cast(h16x2, a),
                                  __builtin_bit_cast(h16x2, b), c, false);
#else
    h16x2 av = __builtin_bit_cast(h16x2, a);
    h16x2 bv = __builtin_bit_cast(h16x2, b);
    return fmaf((float)av[0], (float)bv[0], fmaf((float)av[1], (float)bv[1], c));
#endif
}

// largest i with off(i) = i*(511-i)/2 <= p   (strict-upper triu row index)
__device__ __forceinline__ int row_of(int p) {
    int i = (int)(255.5f - sqrtf(65280.25f - 2.0f * (float)p));
    i = i < 0 ? 0 : (i > 254 ? 254 : i);
    while ((i + 1) * (510 - i) / 2 <= p) ++i;
    while (i > 0 && i * (511 - i) / 2 > p) --i;
    return i;
}

__device__ __forceinline__ int yidx(int m) { return (m >> 6) * PSH + (m & 63); }

__global__ void __launch_bounds__(1024)
cayley_kernel(const float* __restrict__ x, const float* __restrict__ W,
              float* __restrict__ out) {
    extern __shared__ char smem[];
    h16*   sS  = (h16*)smem;                             // 256*288*2 = 147456 B
    h16*   sy0 = (h16*)(smem + DIM * RSH * 2);           // 288*2 = 576 B
    h16*   sy1 = sy0 + RSH;                              // 576 B
    float* sx  = (float*)(smem + DIM * RSH * 2 + 2 * RSH * 2); // 1024 B

    const int tid = threadIdx.x;
    const int c   = blockIdx.x;

    if (tid < DIM) {
        float xv = x[(size_t)tid * CLS + c];
        sx[tid]  = xv;
        sy0[yidx(tid)] = (h16)xv;
        sS[tid * RSH + yidx(tid)] = (h16)0.f;            // zero diagonal
    }

    // ---- expand packed strict-upper W into full f16 skew matrix in LDS ----
    const float4* Wc4 = (const float4*)(W + (size_t)c * NGF);
    for (int q = tid; q < NGF / 4; q += 1024) {
        float4 w4 = Wc4[q];                               // coalesced 16B/lane
        float wv[4] = {w4.x, w4.y, w4.z, w4.w};
        int p0 = q * 4;
        #pragma unroll
        for (int e = 0; e < 4; ++e) {
            int pp = p0 + e;
            int i  = row_of(pp);
            int j  = pp - i * (511 - i) / 2 + i + 1;
            float s = 0.5f * wv[e];
            sS[i * RSH + yidx(j)] = (h16)s;               // S[i][j] = +0.5 w
            sS[j * RSH + yidx(i)] = (h16)(-s);            // S[j][i] = -0.5 w
        }
    }
    __syncthreads();

    // ---- 4 threads per row: 64-elem partial dot each, shfl-combined ----
    const int r = tid >> 2;          // row 0..255
    const int p = tid & 3;           // part 0..3 (columns 64p .. 64p+63)
    const uint4* rowp = (const uint4*)(sS + r * RSH + p * PSH);
    const float  xr   = sx[r];

    h16* ycur = sy0;
    h16* ynxt = sy1;

    for (int it = 0; it < NITER; ++it) {
        const uint4* yp = (const uint4*)(ycur + p * PSH);
        float a0 = 0.f, a1 = 0.f, a2 = 0.f, a3 = 0.f;
        #pragma unroll
        for (int k = 0; k < 8; ++k) {
            uint4 rv = rowp[k];
            uint4 yv = yp[k];
            a0 = dot2f(rv.x, yv.x, a0);
            a1 = dot2f(rv.y, yv.y, a1);
            a2 = dot2f(rv.z, yv.z, a2);
            a3 = dot2f(rv.w, yv.w, a3);
        }
        float v = (a0 + a1) + (a2 + a3);                  // partial (S y)_r
        v += __shfl_xor(v, 1);
        v += __shfl_xor(v, 2);                            // full (S y)_r on all 4 lanes
        if (it < NITER - 1) {
            if (p == 0) ynxt[yidx(r)] = (h16)(xr - v);
            h16* t = ycur; ycur = ynxt; ynxt = t;
            __syncthreads();
        } else {
            if (p == 0) out[(size_t)r * CLS + c] = xr - 2.0f * v;  // out = 2y - x
        }
    }
}

extern "C" void kernel_launch(void* const* d_in, const int* in_sizes, int n_in,
                              void* d_out, int out_size, void* d_ws, size_t ws_size,
                              hipStream_t stream) {
    const float* x = (const float*)d_in[0];
    const float* W = (const float*)d_in[1];
    float* out = (float*)d_out;

    const size_t smem = (size_t)DIM * RSH * 2 + 2 * RSH * 2 + DIM * 4; // 149632 B
    hipFuncSetAttribute((const void*)cayley_kernel,
                        hipFuncAttributeMaxDynamicSharedMemorySize, (int)smem);
    hipLaunchKernelGGL(cayley_kernel, dim3(CLS), dim3(1024), smem, stream, x, W, out);
}